// Round 13
// baseline (1168.330 us; speedup 1.0000x reference)
//
#include <hip/hip_runtime.h>
#include <cstdint>

#define HID 256
#define HEADS 4
#define GRAPHS 64
#define OUTC 32
#define EPSV 1e-5f
#define PSPLIT 32

typedef __bf16 b16x8 __attribute__((ext_vector_type(8)));
typedef float  f32x4 __attribute__((ext_vector_type(4)));

__device__ __forceinline__ f32x4 mfma16(b16x8 a, b16x8 b, f32x4 c) {
    return __builtin_amdgcn_mfma_f32_16x16x32_bf16(a, b, c, 0, 0, 0);
}

__device__ __forceinline__ unsigned int pack_bf16(float a, float b) {
    unsigned short ua = __builtin_bit_cast(unsigned short, (__bf16)a);
    unsigned short ub = __builtin_bit_cast(unsigned short, (__bf16)b);
    return (unsigned int)ua | ((unsigned int)ub << 16);
}

__device__ __forceinline__ void unpack2(unsigned int u, float& lo, float& hi) {
    lo = __builtin_bit_cast(float, u << 16);
    hi = __builtin_bit_cast(float, u & 0xffff0000u);
}

__device__ __forceinline__ float b2f(unsigned short u) {
    return __builtin_bit_cast(float, (unsigned int)u << 16);
}

// ---- async stage of a 128x256 bf16 tile: global -> LDS (linear dest, pre-swizzled src) ----
__device__ __forceinline__ void stage_gld128(char* buf, const unsigned short* __restrict__ src,
                                             int base, int tid)
{
#pragma unroll
    for (int i = 0; i < 16; i++) {
        int idx = i * 256 + tid;
        int r = idx >> 5;
        int u = idx & 31;
        int us = u ^ (r & 7);
        const void* gp = (const void*)(src + (size_t)(base + r) * HID + us * 8);
        __builtin_amdgcn_global_load_lds(
            (const __attribute__((address_space(1))) void*)gp,
            (__attribute__((address_space(3))) void*)(buf + idx * 16),
            16, 0, 0);
    }
}

// ---------------- merged weight transpose + bf16 convert (single launch) ----------------
__global__ __launch_bounds__(256) void wtrans_all(
    const float* __restrict__ e1, const float* __restrict__ e2,
    const float* __restrict__ q,  const float* __restrict__ k,
    const float* __restrict__ v,  const float* __restrict__ m1,
    const float* __restrict__ m2,
    unsigned short* __restrict__ we1, unsigned short* __restrict__ we2,
    unsigned short* __restrict__ wq,  unsigned short* __restrict__ wk,
    unsigned short* __restrict__ wv,  unsigned short* __restrict__ wm1,
    unsigned short* __restrict__ wm2)
{
    __shared__ float tile[32][33];
    int z = blockIdx.z;
    const float* W; unsigned short* Wt; int K; int mat = 0;
    if (z == 0)      { W = e1; Wt = we1; K = 128; }
    else if (z == 1) { W = e2; Wt = we2; K = 256; }
    else if (z < 6)  { W = q;  Wt = wq;  K = 256; mat = z - 2; }
    else if (z < 10) { W = k;  Wt = wk;  K = 256; mat = z - 6; }
    else if (z < 14) { W = v;  Wt = wv;  K = 256; mat = z - 10; }
    else if (z < 18) { W = m1; Wt = wm1; K = 512; mat = z - 14; }
    else             { W = m2; Wt = wm2; K = 256; mat = z - 18; }
    int k0 = blockIdx.x * 32;
    if (k0 >= K) return;
    const int C = 256;
    W  += (size_t)mat * K * C;
    Wt += (size_t)mat * K * C;
    int c0 = blockIdx.y * 32;
    int tx = threadIdx.x & 31, ty = threadIdx.x >> 5;
#pragma unroll
    for (int i = 0; i < 32; i += 8)
        tile[ty + i][tx] = W[(size_t)(k0 + ty + i) * C + c0 + tx];
    __syncthreads();
#pragma unroll
    for (int i = 0; i < 32; i += 8) {
        float vv = tile[tx][ty + i];
        Wt[(size_t)(c0 + ty + i) * K + k0 + tx] =
            __builtin_bit_cast(unsigned short, (__bf16)vv);
    }
}

// ---------------- enc1: fp32 in (x, K=128), bf16 out, ReLU+LN (64-row tile) ----------------
__global__ __launch_bounds__(256) void enc1_mfma(
    const float* __restrict__ in0, const unsigned short* __restrict__ Wt,
    const float* __restrict__ bias, const float* __restrict__ g,
    const float* __restrict__ be, unsigned short* __restrict__ outb, int n)
{
    constexpr int KTILE = 128, ROWB = 256;
    __shared__ __align__(16) char alds[64 * 256];
    __shared__ float red[4][64][2];
    int tid = threadIdx.x, lane = tid & 63, wv = tid >> 6;
    int cg = lane & 15, rg = lane >> 4;
    int base = blockIdx.x * 64;
    int cbase = wv * 64;

    f32x4 acc[4][4];
#pragma unroll
    for (int m = 0; m < 4; m++)
#pragma unroll
        for (int f = 0; f < 4; f++) acc[m][f] = (f32x4){0.f, 0.f, 0.f, 0.f};

#pragma unroll
    for (int i = 0; i < 8; i++) {
        int idx = (i * 256 + tid) * 4;
        int row = idx >> 7, k = idx & 127;
        int node = base + row;
        float4 v = {0.f, 0.f, 0.f, 0.f};
        if (node < n) v = *(const float4*)(in0 + (size_t)node * KTILE + k);
        uint2 pp; pp.x = pack_bf16(v.x, v.y); pp.y = pack_bf16(v.z, v.w);
        int off = row * ROWB + k * 2;
        off ^= (row & 7) << 4;
        *(uint2*)(alds + off) = pp;
    }
    __syncthreads();

#pragma unroll 2
    for (int k0 = 0; k0 < KTILE; k0 += 32) {
        b16x8 a[4], b[4];
#pragma unroll
        for (int m = 0; m < 4; m++) {
            int R = m * 16 + cg;
            int off = R * ROWB + (k0 + rg * 8) * 2;
            off ^= (R & 7) << 4;
            a[m] = __builtin_bit_cast(b16x8, *(const uint4*)(alds + off));
        }
#pragma unroll
        for (int f = 0; f < 4; f++) {
            const unsigned short* p = Wt + (size_t)(cbase + f * 16 + cg) * KTILE + k0 + rg * 8;
            b[f] = __builtin_bit_cast(b16x8, *(const uint4*)p);
        }
#pragma unroll
        for (int m = 0; m < 4; m++)
#pragma unroll
            for (int f = 0; f < 4; f++)
                acc[m][f] = mfma16(a[m], b[f], acc[m][f]);
    }

    float bias_v[4], g_v[4], be_v[4];
#pragma unroll
    for (int f = 0; f < 4; f++) {
        int col = cbase + f * 16 + cg;
        bias_v[f] = bias[col]; g_v[f] = g[col]; be_v[f] = be[col];
    }
#pragma unroll
    for (int m = 0; m < 4; m++)
#pragma unroll
        for (int f = 0; f < 4; f++)
#pragma unroll
            for (int r = 0; r < 4; r++)
                acc[m][f][r] = fmaxf(acc[m][f][r] + bias_v[f], 0.f);
#pragma unroll
    for (int m = 0; m < 4; m++)
#pragma unroll
        for (int r = 0; r < 4; r++) {
            float s = acc[m][0][r] + acc[m][1][r] + acc[m][2][r] + acc[m][3][r];
            float q = acc[m][0][r] * acc[m][0][r] + acc[m][1][r] * acc[m][1][r]
                    + acc[m][2][r] * acc[m][2][r] + acc[m][3][r] * acc[m][3][r];
#pragma unroll
            for (int o = 1; o < 16; o <<= 1) {
                s += __shfl_xor(s, o, 64); q += __shfl_xor(q, o, 64);
            }
            if (cg == 0) { int R = m * 16 + rg * 4 + r; red[wv][R][0] = s; red[wv][R][1] = q; }
        }
    __syncthreads();
#pragma unroll
    for (int m = 0; m < 4; m++)
#pragma unroll
        for (int r = 0; r < 4; r++) {
            int R = m * 16 + rg * 4 + r;
            float S = red[0][R][0] + red[1][R][0] + red[2][R][0] + red[3][R][0];
            float Q = red[0][R][1] + red[1][R][1] + red[2][R][1] + red[3][R][1];
            float mu = S * (1.f / HID);
            float rs = rsqrtf(Q * (1.f / HID) - mu * mu + EPSV);
            int row = base + R;
            if (row >= n) continue;
            size_t ro = (size_t)row * HID;
#pragma unroll
            for (int f = 0; f < 4; f++) {
                float v = (acc[m][f][r] - mu) * rs * g_v[f] + be_v[f];
                outb[ro + cbase + f * 16 + cg] = __builtin_bit_cast(unsigned short, (__bf16)v);
            }
        }
}

// ---------------- 128-row MFMA GEMM, bf16 in/out ----------------
template<int NPASS, bool RELU_LN, bool ADD_RES, bool POS>
__global__ __launch_bounds__(256) void gemm128(
    const unsigned short* __restrict__ in0, const unsigned short* __restrict__ in1,
    const unsigned short* __restrict__ Wt, const float* __restrict__ bias,
    const float* __restrict__ g, const float* __restrict__ be,
    const unsigned short* __restrict__ addsrc, const float* __restrict__ pos_emb,
    const int* __restrict__ pidx, unsigned short* __restrict__ outb, int n)
{
    constexpr int KS = 256 * NPASS;
    __shared__ __align__(16) char alds[128 * 512];   // 64 KB
    __shared__ float red[4][128][2];

    int tid = threadIdx.x, lane = tid & 63, wv = tid >> 6;
    int cg = lane & 15, rg = lane >> 4;
    int base = blockIdx.x * 128;
    int cbase = wv * 64;

    f32x4 acc[2][4][4];
#pragma unroll
    for (int t = 0; t < 2; t++)
#pragma unroll
        for (int m = 0; m < 4; m++)
#pragma unroll
            for (int f = 0; f < 4; f++) acc[t][m][f] = (f32x4){0.f, 0.f, 0.f, 0.f};

    for (int pass = 0; pass < NPASS; pass++) {
        if (pass) __syncthreads();
        const unsigned short* src = pass ? in1 : in0;
        const unsigned short* Wp = Wt + pass * 256;

        stage_gld128(alds, src, base, tid);
        __syncthreads();

#pragma unroll
        for (int kk = 0; kk < 8; kk++) {
            b16x8 b[4];
#pragma unroll
            for (int f = 0; f < 4; f++)
                b[f] = __builtin_bit_cast(b16x8, *(const uint4*)(
                    Wp + (size_t)(cbase + f * 16 + cg) * KS + kk * 32 + rg * 8));
#pragma unroll
            for (int t = 0; t < 2; t++) {
                b16x8 a[4];
#pragma unroll
                for (int m = 0; m < 4; m++) {
                    int R = t * 64 + m * 16 + cg;
                    int off = R * 512 + (kk * 32 + rg * 8) * 2;
                    off ^= (R & 7) << 4;
                    a[m] = __builtin_bit_cast(b16x8, *(const uint4*)(alds + off));
                }
#pragma unroll
                for (int m = 0; m < 4; m++)
#pragma unroll
                    for (int f = 0; f < 4; f++)
                        acc[t][m][f] = mfma16(a[m], b[f], acc[t][m][f]);
            }
        }
    }

    float bias_v[4], g_v[4], be_v[4];
#pragma unroll
    for (int f = 0; f < 4; f++) {
        int col = cbase + f * 16 + cg;
        bias_v[f] = bias[col];
        if (RELU_LN) { g_v[f] = g[col]; be_v[f] = be[col]; }
    }
#pragma unroll
    for (int t = 0; t < 2; t++)
#pragma unroll
        for (int m = 0; m < 4; m++)
#pragma unroll
            for (int f = 0; f < 4; f++)
#pragma unroll
                for (int r = 0; r < 4; r++) acc[t][m][f][r] += bias_v[f];

    if (RELU_LN) {
#pragma unroll
        for (int t = 0; t < 2; t++)
#pragma unroll
            for (int m = 0; m < 4; m++)
#pragma unroll
                for (int f = 0; f < 4; f++)
#pragma unroll
                    for (int r = 0; r < 4; r++)
                        acc[t][m][f][r] = fmaxf(acc[t][m][f][r], 0.f);
#pragma unroll
        for (int t = 0; t < 2; t++)
#pragma unroll
            for (int m = 0; m < 4; m++)
#pragma unroll
                for (int r = 0; r < 4; r++) {
                    float s = acc[t][m][0][r] + acc[t][m][1][r] + acc[t][m][2][r] + acc[t][m][3][r];
                    float q = acc[t][m][0][r] * acc[t][m][0][r] + acc[t][m][1][r] * acc[t][m][1][r]
                            + acc[t][m][2][r] * acc[t][m][2][r] + acc[t][m][3][r] * acc[t][m][3][r];
#pragma unroll
                    for (int o = 1; o < 16; o <<= 1) {
                        s += __shfl_xor(s, o, 64); q += __shfl_xor(q, o, 64);
                    }
                    if (cg == 0) {
                        int R = t * 64 + m * 16 + rg * 4 + r;
                        red[wv][R][0] = s; red[wv][R][1] = q;
                    }
                }
        __syncthreads();
#pragma unroll
        for (int t = 0; t < 2; t++)
#pragma unroll
            for (int m = 0; m < 4; m++)
#pragma unroll
                for (int r = 0; r < 4; r++) {
                    int R = t * 64 + m * 16 + rg * 4 + r;
                    float S = red[0][R][0] + red[1][R][0] + red[2][R][0] + red[3][R][0];
                    float Q = red[0][R][1] + red[1][R][1] + red[2][R][1] + red[3][R][1];
                    float mu = S * (1.f / HID);
                    float rs = rsqrtf(Q * (1.f / HID) - mu * mu + EPSV);
#pragma unroll
                    for (int f = 0; f < 4; f++)
                        acc[t][m][f][r] = (acc[t][m][f][r] - mu) * rs * g_v[f] + be_v[f];
                }
    }

#pragma unroll
    for (int t = 0; t < 2; t++)
#pragma unroll
        for (int m = 0; m < 4; m++)
#pragma unroll
            for (int r = 0; r < 4; r++) {
                int row = base + t * 64 + m * 16 + rg * 4 + r;
                if (row >= n) continue;
                size_t ro = (size_t)row * HID;
                int pid = 0;
                if (POS) pid = pidx[row];
#pragma unroll
                for (int f = 0; f < 4; f++) {
                    int col = cbase + f * 16 + cg;
                    float v = acc[t][m][f][r];
                    if (ADD_RES) v += b2f(addsrc[ro + col]);
                    if (POS)     v += pos_emb[(size_t)pid * HID + col];
                    outb[ro + col] = __builtin_bit_cast(unsigned short, (__bf16)v);
                }
            }
}

// ---------------- fused MLP: mlp1(K=512) -> LN -> (LDS) -> mlp2 + residual ----------------
__global__ __launch_bounds__(256) void mlp_fused(
    const unsigned short* __restrict__ h16, const unsigned short* __restrict__ a16,
    const unsigned short* __restrict__ Wt1, const float* __restrict__ b1,
    const float* __restrict__ g, const float* __restrict__ be,
    const unsigned short* __restrict__ Wt2, const float* __restrict__ b2,
    unsigned short* __restrict__ hout, int n)
{
    __shared__ __align__(16) char alds[128 * 512];   // 64 KB
    __shared__ float red[4][128][2];
    int tid = threadIdx.x, lane = tid & 63, wv = tid >> 6;
    int cg = lane & 15, rg = lane >> 4;
    int base = blockIdx.x * 128;
    int cbase = wv * 64;

    f32x4 acc[2][4][4];
#pragma unroll
    for (int t = 0; t < 2; t++)
#pragma unroll
        for (int m = 0; m < 4; m++)
#pragma unroll
            for (int f = 0; f < 4; f++) acc[t][m][f] = (f32x4){0.f, 0.f, 0.f, 0.f};

    for (int pass = 0; pass < 2; pass++) {
        if (pass) __syncthreads();
        const unsigned short* src = pass ? a16 : h16;
        const unsigned short* Wp = Wt1 + pass * 256;
        stage_gld128(alds, src, base, tid);
        __syncthreads();
#pragma unroll
        for (int kk = 0; kk < 8; kk++) {
            b16x8 b[4];
#pragma unroll
            for (int f = 0; f < 4; f++)
                b[f] = __builtin_bit_cast(b16x8, *(const uint4*)(
                    Wp + (size_t)(cbase + f * 16 + cg) * 512 + kk * 32 + rg * 8));
#pragma unroll
            for (int t = 0; t < 2; t++) {
                b16x8 a[4];
#pragma unroll
                for (int m = 0; m < 4; m++) {
                    int R = t * 64 + m * 16 + cg;
                    int off = R * 512 + (kk * 32 + rg * 8) * 2;
                    off ^= (R & 7) << 4;
                    a[m] = __builtin_bit_cast(b16x8, *(const uint4*)(alds + off));
                }
#pragma unroll
                for (int m = 0; m < 4; m++)
#pragma unroll
                    for (int f = 0; f < 4; f++)
                        acc[t][m][f] = mfma16(a[m], b[f], acc[t][m][f]);
            }
        }
    }

    float b1_v[4], g_v[4], be_v[4];
#pragma unroll
    for (int f = 0; f < 4; f++) {
        int col = cbase + f * 16 + cg;
        b1_v[f] = b1[col]; g_v[f] = g[col]; be_v[f] = be[col];
    }
#pragma unroll
    for (int t = 0; t < 2; t++)
#pragma unroll
        for (int m = 0; m < 4; m++)
#pragma unroll
            for (int f = 0; f < 4; f++)
#pragma unroll
                for (int r = 0; r < 4; r++)
                    acc[t][m][f][r] = fmaxf(acc[t][m][f][r] + b1_v[f], 0.f);
#pragma unroll
    for (int t = 0; t < 2; t++)
#pragma unroll
        for (int m = 0; m < 4; m++)
#pragma unroll
            for (int r = 0; r < 4; r++) {
                float s = acc[t][m][0][r] + acc[t][m][1][r] + acc[t][m][2][r] + acc[t][m][3][r];
                float q = acc[t][m][0][r] * acc[t][m][0][r] + acc[t][m][1][r] * acc[t][m][1][r]
                        + acc[t][m][2][r] * acc[t][m][2][r] + acc[t][m][3][r] * acc[t][m][3][r];
#pragma unroll
                for (int o = 1; o < 16; o <<= 1) {
                    s += __shfl_xor(s, o, 64); q += __shfl_xor(q, o, 64);
                }
                if (cg == 0) {
                    int R = t * 64 + m * 16 + rg * 4 + r;
                    red[wv][R][0] = s; red[wv][R][1] = q;
                }
            }
    __syncthreads();
#pragma unroll
    for (int t = 0; t < 2; t++)
#pragma unroll
        for (int m = 0; m < 4; m++)
#pragma unroll
            for (int r = 0; r < 4; r++) {
                int R = t * 64 + m * 16 + rg * 4 + r;
                float S = red[0][R][0] + red[1][R][0] + red[2][R][0] + red[3][R][0];
                float Q = red[0][R][1] + red[1][R][1] + red[2][R][1] + red[3][R][1];
                float mu = S * (1.f / HID);
                float rs = rsqrtf(Q * (1.f / HID) - mu * mu + EPSV);
#pragma unroll
                for (int f = 0; f < 4; f++)
                    acc[t][m][f][r] = (acc[t][m][f][r] - mu) * rs * g_v[f] + be_v[f];
            }

    __syncthreads();
#pragma unroll
    for (int t = 0; t < 2; t++)
#pragma unroll
        for (int m = 0; m < 4; m++)
#pragma unroll
            for (int r = 0; r < 4; r++) {
                int R = t * 64 + m * 16 + rg * 4 + r;
#pragma unroll
                for (int f = 0; f < 4; f++) {
                    int col = cbase + f * 16 + cg;
                    int off = R * 512 + col * 2;
                    off ^= (R & 7) << 4;
                    *(unsigned short*)(alds + off) =
                        __builtin_bit_cast(unsigned short, (__bf16)acc[t][m][f][r]);
                }
            }
    __syncthreads();

#pragma unroll
    for (int t = 0; t < 2; t++)
#pragma unroll
        for (int m = 0; m < 4; m++)
#pragma unroll
            for (int f = 0; f < 4; f++) acc[t][m][f] = (f32x4){0.f, 0.f, 0.f, 0.f};
#pragma unroll
    for (int kk = 0; kk < 8; kk++) {
        b16x8 b[4];
#pragma unroll
        for (int f = 0; f < 4; f++)
            b[f] = __builtin_bit_cast(b16x8, *(const uint4*)(
                Wt2 + (size_t)(cbase + f * 16 + cg) * 256 + kk * 32 + rg * 8));
#pragma unroll
        for (int t = 0; t < 2; t++) {
            b16x8 a[4];
#pragma unroll
            for (int m = 0; m < 4; m++) {
                int R = t * 64 + m * 16 + cg;
                int off = R * 512 + (kk * 32 + rg * 8) * 2;
                off ^= (R & 7) << 4;
                a[m] = __builtin_bit_cast(b16x8, *(const uint4*)(alds + off));
            }
#pragma unroll
            for (int m = 0; m < 4; m++)
#pragma unroll
                for (int f = 0; f < 4; f++)
                    acc[t][m][f] = mfma16(a[m], b[f], acc[t][m][f]);
        }
    }

    float b2_v[4];
#pragma unroll
    for (int f = 0; f < 4; f++) b2_v[f] = b2[cbase + f * 16 + cg];
#pragma unroll
    for (int t = 0; t < 2; t++)
#pragma unroll
        for (int m = 0; m < 4; m++)
#pragma unroll
            for (int r = 0; r < 4; r++) {
                int row = base + t * 64 + m * 16 + rg * 4 + r;
                if (row >= n) continue;
                size_t ro = (size_t)row * HID;
#pragma unroll
                for (int f = 0; f < 4; f++) {
                    int col = cbase + f * 16 + cg;
                    float v = acc[t][m][f][r] + b2_v[f] + b2f(hout[ro + col]);
                    hout[ro + col] = __builtin_bit_cast(unsigned short, (__bf16)v);
                }
            }
}

// ---------------- QKV, 128-row tile, 3-way split; K/V interleaved into KV[node][512] ----------------
__global__ __launch_bounds__(256) void qkv128_kernel(
    const unsigned short* __restrict__ hsrc,
    const unsigned short* __restrict__ Wtq, const unsigned short* __restrict__ Wtk,
    const unsigned short* __restrict__ Wtv,
    const float* __restrict__ bq, const float* __restrict__ bk, const float* __restrict__ bv,
    unsigned short* __restrict__ Qo, unsigned short* __restrict__ KVo, int n)
{
    __shared__ __align__(16) char alds[128 * 512];   // 64 KB
    int tid = threadIdx.x, lane = tid & 63, wv = tid >> 6;
    int cg = lane & 15, rg = lane >> 4;
    int base = blockIdx.x * 128;
    int cbase = wv * 64;
    int mat = blockIdx.y;
    const unsigned short* Wp = (mat == 0) ? Wtq : (mat == 1) ? Wtk : Wtv;
    const float* bp = (mat == 0) ? bq : (mat == 1) ? bk : bv;
    unsigned short* op = (mat == 0) ? Qo : KVo;
    int ostride = (mat == 0) ? HID : 512;
    int coff = (mat == 2) ? 256 : 0;

    stage_gld128(alds, hsrc, base, tid);
    __syncthreads();

    f32x4 acc[2][4][4];
#pragma unroll
    for (int t = 0; t < 2; t++)
#pragma unroll
        for (int m = 0; m < 4; m++)
#pragma unroll
            for (int f = 0; f < 4; f++) acc[t][m][f] = (f32x4){0.f, 0.f, 0.f, 0.f};

#pragma unroll
    for (int kk = 0; kk < 8; kk++) {
        b16x8 b[4];
#pragma unroll
        for (int f = 0; f < 4; f++)
            b[f] = __builtin_bit_cast(b16x8, *(const uint4*)(
                Wp + (size_t)(cbase + f * 16 + cg) * 256 + kk * 32 + rg * 8));
#pragma unroll
        for (int t = 0; t < 2; t++) {
            b16x8 a[4];
#pragma unroll
            for (int m = 0; m < 4; m++) {
                int R = t * 64 + m * 16 + cg;
                int off = R * 512 + (kk * 32 + rg * 8) * 2;
                off ^= (R & 7) << 4;
                a[m] = __builtin_bit_cast(b16x8, *(const uint4*)(alds + off));
            }
#pragma unroll
            for (int m = 0; m < 4; m++)
#pragma unroll
                for (int f = 0; f < 4; f++)
                    acc[t][m][f] = mfma16(a[m], b[f], acc[t][m][f]);
        }
    }

    float bias_v[4];
#pragma unroll
    for (int f = 0; f < 4; f++) bias_v[f] = bp[cbase + f * 16 + cg];
#pragma unroll
    for (int t = 0; t < 2; t++)
#pragma unroll
        for (int m = 0; m < 4; m++)
#pragma unroll
            for (int r = 0; r < 4; r++) {
                int row = base + t * 64 + m * 16 + rg * 4 + r;
                if (row >= n) continue;
                size_t ro = (size_t)row * ostride + coff;
#pragma unroll
                for (int f = 0; f < 4; f++) {
                    float v = acc[t][m][f][r] + bias_v[f];
                    op[ro + cbase + f * 16 + cg] =
                        __builtin_bit_cast(unsigned short, (__bf16)v);
                }
            }
}

// ---------------- CSR build ----------------
__global__ void count_kernel(const int* __restrict__ row, int* __restrict__ counts, int e)
{
    int i = blockIdx.x * blockDim.x + threadIdx.x;
    if (i < e) atomicAdd(&counts[row[i]], 1);
}

__global__ __launch_bounds__(256) void scan1_kernel(const int* __restrict__ counts,
    int* __restrict__ offs, int* __restrict__ bsum, int n)
{
    __shared__ int wsumS[4];
    int tid = threadIdx.x, b = blockIdx.x;
    int i = b * 256 + tid;
    int v = (i < n) ? counts[i] : 0;
    int lane = tid & 63, wv = tid >> 6;
    int s = v;
#pragma unroll
    for (int o = 1; o < 64; o <<= 1) { int t = __shfl_up(s, o, 64); if (lane >= o) s += t; }
    if (lane == 63) wsumS[wv] = s;
    __syncthreads();
    int add = 0;
    for (int j = 0; j < wv; j++) add += wsumS[j];
    s += add;
    if (i < n) offs[i + 1] = s;
    if (tid == 255) bsum[b] = s;
}

__global__ __launch_bounds__(256) void scan2_kernel(int* __restrict__ bsum, int nb)
{
    __shared__ int wsumS[4];
    int tid = threadIdx.x;
    int v = (tid < nb) ? bsum[tid] : 0;
    int lane = tid & 63, wv = tid >> 6;
    int s = v;
#pragma unroll
    for (int o = 1; o < 64; o <<= 1) { int t = __shfl_up(s, o, 64); if (lane >= o) s += t; }
    if (lane == 63) wsumS[wv] = s;
    __syncthreads();
    int add = 0;
    for (int j = 0; j < wv; j++) add += wsumS[j];
    s += add;
    if (tid < nb) bsum[tid] = s;
}

__global__ __launch_bounds__(256) void scan3_kernel(int* __restrict__ offs,
    const int* __restrict__ bsum, int n)
{
    int tid = threadIdx.x, b = blockIdx.x;
    int i = b * 256 + tid;
    if (i == 0) offs[0] = 0;
    if (i < n && b > 0) offs[i + 1] += bsum[b - 1];
}

__global__ void scatter_kernel(const int* __restrict__ row, const int* __restrict__ col,
    const int* __restrict__ offs, int* __restrict__ cur, int* __restrict__ ccol, int e)
{
    int i = blockIdx.x * blockDim.x + threadIdx.x;
    if (i >= e) return;
    int r = row[i];
    int pos = atomicAdd(&cur[r], 1);
    ccol[offs[r] + pos] = col[i];
}

// ---------------- attention: full wave per node, 2-way edge split, interleaved KV ----------------
__global__ __launch_bounds__(256) void attn_fw_kernel(
    const unsigned short* __restrict__ Qm, const unsigned short* __restrict__ KV,
    const int* __restrict__ offs, const int* __restrict__ ccol,
    unsigned short* __restrict__ agg, int n)
{
    int tid = threadIdx.x;
    int wv = tid >> 6;
    int lane = tid & 63;
    int half = lane >> 5;
    int l32 = lane & 31;
    int node = blockIdx.x * 4 + wv;
    if (node >= n) return;
    int start = offs[node], fin = offs[node + 1];
    size_t rowoff = (size_t)node * HID + l32 * 8;
    if (start == fin) {
        if (half == 0) {
            uint4 z = {0u, 0u, 0u, 0u};
            *(uint4*)(agg + rowoff) = z;
        }
        return;
    }

    uint4 qr = *(const uint4*)(Qm + rowoff);
    float qf[8];
    unpack2(qr.x, qf[0], qf[1]);
    unpack2(qr.y, qf[2], qf[3]);
    unpack2(qr.z, qf[4], qf[5]);
    unpack2(qr.w, qf[6], qf[7]);

    float m = -3.0e38f, d = 0.f;
    float acc[8];
#pragma unroll
    for (int j = 0; j < 8; j++) acc[j] = 0.f;

    for (int i = start + half; i < fin; i += 2) {
        int c = ccol[i];
        const unsigned short* kvp = KV + (size_t)c * 512 + l32 * 8;
        uint4 kr = *(const uint4*)kvp;           // K row at [0,256)
        uint4 vr = *(const uint4*)(kvp + 256);   // V row at [256,512)
        float k0, k1, k2, k3, k4, k5, k6, k7;
        unpack2(kr.x, k0, k1); unpack2(kr.y, k2, k3);
        unpack2(kr.z, k4, k5); unpack2(kr.w, k6, k7);
        float p = qf[0] * k0 + qf[1] * k1 + qf[2] * k2 + qf[3] * k3
                + qf[4] * k4 + qf[5] * k5 + qf[6] * k6 + qf[7] * k7;
        p += __shfl_xor(p, 1, 64);
        p += __shfl_xor(p, 2, 64);
        p += __shfl_xor(p, 4, 64);
        float s = p * 0.125f;
        float mn = fmaxf(m, s);
        float sc = __expf(m - mn);
        float w = __expf(s - mn);
        d = d * sc + w;
        float v0, v1, v2, v3, v4, v5, v6, v7;
        unpack2(vr.x, v0, v1); unpack2(vr.y, v2, v3);
        unpack2(vr.z, v4, v5); unpack2(vr.w, v6, v7);
        acc[0] = acc[0] * sc + w * v0;  acc[1] = acc[1] * sc + w * v1;
        acc[2] = acc[2] * sc + w * v2;  acc[3] = acc[3] * sc + w * v3;
        acc[4] = acc[4] * sc + w * v4;  acc[5] = acc[5] * sc + w * v5;
        acc[6] = acc[6] * sc + w * v6;  acc[7] = acc[7] * sc + w * v7;
        m = mn;
    }

    // merge the two halves (exact partial-softmax combination)
    float mo = __shfl_xor(m, 32, 64);
    float M = fmaxf(m, mo);
    float fs = __expf(m - M);
    float fo = __expf(mo - M);
    float D = d * fs + __shfl_xor(d, 32, 64) * fo;
    float inv = 1.f / D;
#pragma unroll
    for (int j = 0; j < 8; j++) {
        float other = __shfl_xor(acc[j], 32, 64);
        acc[j] = (acc[j] * fs + other * fo) * inv;
    }

    if (half == 0) {
        uint4 out;
        out.x = pack_bf16(acc[0], acc[1]);
        out.y = pack_bf16(acc[2], acc[3]);
        out.z = pack_bf16(acc[4], acc[5]);
        out.w = pack_bf16(acc[6], acc[7]);
        *(uint4*)(agg + rowoff) = out;
    }
}

// ---------------- pooling (two-stage parallel, bf16 input) ----------------
__global__ void bounds_kernel(const int* __restrict__ batch, int* __restrict__ gb, int n)
{
    int g = threadIdx.x;
    if (g > GRAPHS) return;
    int lo = 0, hi = n;
    while (lo < hi) { int mid = (lo + hi) >> 1; if (batch[mid] < g) lo = mid + 1; else hi = mid; }
    gb[g] = lo;
}

__global__ __launch_bounds__(256) void pool_partial_kernel(
    const unsigned short* __restrict__ h16,
    const int* __restrict__ gb, float* __restrict__ partial)
{
    int s = blockIdx.x, g = blockIdx.y, tid = threadIdx.x;
    int lo = gb[g], hi = gb[g + 1];
    float sum = 0.f;
    for (int i = lo + s; i < hi; i += PSPLIT)
        sum += b2f(h16[(size_t)i * HID + tid]);
    partial[((size_t)g * PSPLIT + s) * HID + tid] = sum;
}

__global__ __launch_bounds__(256) void pool_reduce_kernel(const float* __restrict__ partial,
    const int* __restrict__ gb, float* __restrict__ pooled)
{
    int g = blockIdx.x, tid = threadIdx.x;
    float sum = 0.f;
#pragma unroll
    for (int s = 0; s < PSPLIT; s++) sum += partial[((size_t)g * PSPLIT + s) * HID + tid];
    int cnt = gb[g + 1] - gb[g];
    pooled[g * HID + tid] = sum / fmaxf((float)cnt, 1.f);
}

// ---------------- classifier ----------------
__global__ __launch_bounds__(256) void cls_kernel(const float* __restrict__ pooled,
    const float* __restrict__ W1, const float* __restrict__ b1,
    const float* __restrict__ g, const float* __restrict__ be,
    const float* __restrict__ W2, const float* __restrict__ b2,
    float* __restrict__ out)
{
    __shared__ float pin[HID];
    __shared__ float hbuf[HID];
    __shared__ float red2[4][2];
    int tid = threadIdx.x, gi = blockIdx.x;
    int lane = tid & 63, wv = tid >> 6;
    pin[tid] = pooled[gi * HID + tid];
    __syncthreads();
    float acc = 0.f;
    for (int k = 0; k < HID; k++) acc += pin[k] * W1[k * HID + tid];
    acc = fmaxf(acc + b1[tid], 0.f);
    float s = acc, q = acc * acc;
#pragma unroll
    for (int o = 1; o < 64; o <<= 1) { s += __shfl_xor(s, o, 64); q += __shfl_xor(q, o, 64); }
    if (lane == 0) { red2[wv][0] = s; red2[wv][1] = q; }
    __syncthreads();
    float S = red2[0][0] + red2[1][0] + red2[2][0] + red2[3][0];
    float Q = red2[0][1] + red2[1][1] + red2[2][1] + red2[3][1];
    float mu = S * (1.f / HID);
    float rs = rsqrtf(Q * (1.f / HID) - mu * mu + EPSV);
    hbuf[tid] = (acc - mu) * rs * g[tid] + be[tid];
    __syncthreads();
    if (tid < OUTC) {
        float o = 0.f;
        for (int k = 0; k < HID; k++) o += hbuf[k] * W2[k * OUTC + tid];
        out[gi * OUTC + tid] = o + b2[tid];
    }
}

// ---------------- host launch ----------------
extern "C" void kernel_launch(void* const* d_in, const int* in_sizes, int n_in,
                              void* d_out, int out_size, void* d_ws, size_t ws_size,
                              hipStream_t stream)
{
    const float* x        = (const float*)d_in[0];
    const int*   ei       = (const int*)d_in[1];
    const int*   pidx     = (const int*)d_in[2];
    const int*   batch    = (const int*)d_in[3];
    const float* enc_w1   = (const float*)d_in[4];
    const float* enc_b1   = (const float*)d_in[5];
    const float* enc_g    = (const float*)d_in[6];
    const float* enc_beta = (const float*)d_in[7];
    const float* enc_w2   = (const float*)d_in[8];
    const float* enc_b2   = (const float*)d_in[9];
    const float* pos_emb  = (const float*)d_in[10];
    const float* Wq       = (const float*)d_in[11];
    const float* bq       = (const float*)d_in[12];
    const float* Wk       = (const float*)d_in[13];
    const float* bk       = (const float*)d_in[14];
    const float* Wv       = (const float*)d_in[15];
    const float* bv       = (const float*)d_in[16];
    const float* mlp_w1   = (const float*)d_in[17];
    const float* mlp_b1   = (const float*)d_in[18];
    const float* mlp_g    = (const float*)d_in[19];
    const float* mlp_beta = (const float*)d_in[20];
    const float* mlp_w2   = (const float*)d_in[21];
    const float* mlp_b2   = (const float*)d_in[22];
    const float* cls_w1   = (const float*)d_in[23];
    const float* cls_b1   = (const float*)d_in[24];
    const float* cls_g    = (const float*)d_in[25];
    const float* cls_beta = (const float*)d_in[26];
    const float* cls_w2   = (const float*)d_in[27];
    const float* cls_b2   = (const float*)d_in[28];

    int n = in_sizes[2];            // 50000
    int e = in_sizes[1] / 2;        // 800000
    const int* row = ei;
    const int* col = ei + e;

    char* p = (char*)d_ws;
    auto alloc = [&](size_t bytes) -> void* {
        void* r = (void*)p;
        p += (bytes + 255) & ~(size_t)255;
        return r;
    };
    size_t NH = (size_t)n * HID;
    unsigned short* h16  = (unsigned short*)alloc(NH * 2);
    unsigned short* a16  = (unsigned short*)alloc(NH * 2);
    unsigned short* m16  = (unsigned short*)alloc(NH * 2);
    unsigned short* Qb   = (unsigned short*)alloc(NH * 2);
    unsigned short* KVb  = (unsigned short*)alloc(NH * 4);   // K/V interleaved [n][512]
    float* partial = (float*)alloc((size_t)GRAPHS * PSPLIT * HID * 4);
    float* pooled  = (float*)alloc((size_t)GRAPHS * HID * 4);
    int* counts = (int*)alloc((size_t)n * 4);
    int* offs   = (int*)alloc((size_t)(n + 1) * 4);
    int* cur    = (int*)alloc((size_t)n * 4);
    int* ccol   = (int*)alloc((size_t)e * 4);
    int* bsum   = (int*)alloc(1024);
    int* gb     = (int*)alloc((GRAPHS + 1) * 4);
    unsigned short* wt_e1 = (unsigned short*)alloc((size_t)128 * 256 * 2);
    unsigned short* wt_e2 = (unsigned short*)alloc((size_t)256 * 256 * 2);
    unsigned short* wt_q  = (unsigned short*)alloc((size_t)4 * 256 * 256 * 2);
    unsigned short* wt_k  = (unsigned short*)alloc((size_t)4 * 256 * 256 * 2);
    unsigned short* wt_v  = (unsigned short*)alloc((size_t)4 * 256 * 256 * 2);
    unsigned short* wt_m1 = (unsigned short*)alloc((size_t)4 * 512 * 256 * 2);
    unsigned short* wt_m2 = (unsigned short*)alloc((size_t)4 * 256 * 256 * 2);

    int gblocks64  = (n + 63) / 64;
    int gblocks128 = (n + 127) / 128;
    int nb = (n + 255) / 256;

    // ---- weight prep (single launch) ----
    wtrans_all<<<dim3(16, 8, 22), 256, 0, stream>>>(
        enc_w1, enc_w2, Wq, Wk, Wv, mlp_w1, mlp_w2,
        wt_e1, wt_e2, wt_q, wt_k, wt_v, wt_m1, wt_m2);

    // ---- CSR build ----
    hipMemsetAsync(counts, 0, (size_t)n * 4, stream);
    hipMemsetAsync(cur, 0, (size_t)n * 4, stream);
    count_kernel<<<(e + 255) / 256, 256, 0, stream>>>(row, counts, e);
    scan1_kernel<<<nb, 256, 0, stream>>>(counts, offs, bsum, n);
    scan2_kernel<<<1, 256, 0, stream>>>(bsum, nb);
    scan3_kernel<<<nb, 256, 0, stream>>>(offs, bsum, n);
    scatter_kernel<<<(e + 255) / 256, 256, 0, stream>>>(row, col, offs, cur, ccol, e);
    bounds_kernel<<<1, 128, 0, stream>>>(batch, gb, n);

    // ---- encoder ----
    enc1_mfma<<<gblocks64, 256, 0, stream>>>(x, wt_e1, enc_b1, enc_g, enc_beta, m16, n);
    gemm128<1, false, false, true><<<gblocks128, 256, 0, stream>>>(
        m16, nullptr, wt_e2, enc_b2, nullptr, nullptr, nullptr, pos_emb, pidx, h16, n);

    // ---- attention layers ----
    int ablocks = (n + 3) / 4;
    for (int l = 0; l < 4; l++) {
        size_t wo = (size_t)l * 256 * 256;
        size_t bo = (size_t)l * HID;
        qkv128_kernel<<<dim3(gblocks128, 3), 256, 0, stream>>>(
            h16, wt_q + wo, wt_k + wo, wt_v + wo, bq + bo, bk + bo, bv + bo,
            Qb, KVb, n);
        attn_fw_kernel<<<ablocks, 256, 0, stream>>>(Qb, KVb, offs, ccol, a16, n);
        mlp_fused<<<gblocks128, 256, 0, stream>>>(
            h16, a16, wt_m1 + (size_t)l * 512 * 256, mlp_b1 + bo,
            mlp_g + bo, mlp_beta + bo, wt_m2 + wo, mlp_b2 + bo, h16, n);
    }

    // ---- pool + classifier ----
    pool_partial_kernel<<<dim3(PSPLIT, GRAPHS), 256, 0, stream>>>(h16, gb, partial);
    pool_reduce_kernel<<<GRAPHS, 256, 0, stream>>>(partial, gb, pooled);
    cls_kernel<<<GRAPHS, 256, 0, stream>>>(pooled, cls_w1, cls_b1, cls_g, cls_beta,
                                           cls_w2, cls_b2, (float*)d_out);
}

// Round 15
// 1161.217 us; speedup vs baseline: 1.0061x; 1.0061x over previous
//
#include <hip/hip_runtime.h>
#include <cstdint>

#define HID 256
#define HEADS 4
#define GRAPHS 64
#define OUTC 32
#define EPSV 1e-5f
#define PSPLIT 32

typedef __bf16 b16x8 __attribute__((ext_vector_type(8)));
typedef float  f32x4 __attribute__((ext_vector_type(4)));

__device__ __forceinline__ f32x4 mfma16(b16x8 a, b16x8 b, f32x4 c) {
    return __builtin_amdgcn_mfma_f32_16x16x32_bf16(a, b, c, 0, 0, 0);
}

__device__ __forceinline__ unsigned int pack_bf16(float a, float b) {
    unsigned short ua = __builtin_bit_cast(unsigned short, (__bf16)a);
    unsigned short ub = __builtin_bit_cast(unsigned short, (__bf16)b);
    return (unsigned int)ua | ((unsigned int)ub << 16);
}

__device__ __forceinline__ void unpack2(unsigned int u, float& lo, float& hi) {
    lo = __builtin_bit_cast(float, u << 16);
    hi = __builtin_bit_cast(float, u & 0xffff0000u);
}

__device__ __forceinline__ float b2f(unsigned short u) {
    return __builtin_bit_cast(float, (unsigned int)u << 16);
}

// ---- async stage of a 128x256 bf16 tile: global -> LDS (linear dest, pre-swizzled src) ----
__device__ __forceinline__ void stage_gld128(char* buf, const unsigned short* __restrict__ src,
                                             int base, int tid)
{
#pragma unroll
    for (int i = 0; i < 16; i++) {
        int idx = i * 256 + tid;
        int r = idx >> 5;
        int u = idx & 31;
        int us = u ^ (r & 7);
        const void* gp = (const void*)(src + (size_t)(base + r) * HID + us * 8);
        __builtin_amdgcn_global_load_lds(
            (const __attribute__((address_space(1))) void*)gp,
            (__attribute__((address_space(3))) void*)(buf + idx * 16),
            16, 0, 0);
    }
}

// ---- async stage of a 128x128 bf16 HALF-tile (32KB), ROWB=256, pre-swizzled src ----
__device__ __forceinline__ void stage_half(char* buf, const unsigned short* __restrict__ src,
                                           int base, int colbase, int tid)
{
#pragma unroll
    for (int i = 0; i < 8; i++) {
        int idx = i * 256 + tid;
        int r = idx >> 4;
        int u = idx & 15;
        int us = u ^ (r & 7);
        const void* gp = (const void*)(src + (size_t)(base + r) * HID + colbase + us * 8);
        __builtin_amdgcn_global_load_lds(
            (const __attribute__((address_space(1))) void*)gp,
            (__attribute__((address_space(3))) void*)(buf + idx * 16),
            16, 0, 0);
    }
}

// ---------------- merged weight transpose + bf16 convert (single launch) ----------------
__global__ __launch_bounds__(256) void wtrans_all(
    const float* __restrict__ e1, const float* __restrict__ e2,
    const float* __restrict__ q,  const float* __restrict__ k,
    const float* __restrict__ v,  const float* __restrict__ m1,
    const float* __restrict__ m2,
    unsigned short* __restrict__ we1, unsigned short* __restrict__ we2,
    unsigned short* __restrict__ wq,  unsigned short* __restrict__ wk,
    unsigned short* __restrict__ wv,  unsigned short* __restrict__ wm1,
    unsigned short* __restrict__ wm2)
{
    __shared__ float tile[32][33];
    int z = blockIdx.z;
    const float* W; unsigned short* Wt; int K; int mat = 0;
    if (z == 0)      { W = e1; Wt = we1; K = 128; }
    else if (z == 1) { W = e2; Wt = we2; K = 256; }
    else if (z < 6)  { W = q;  Wt = wq;  K = 256; mat = z - 2; }
    else if (z < 10) { W = k;  Wt = wk;  K = 256; mat = z - 6; }
    else if (z < 14) { W = v;  Wt = wv;  K = 256; mat = z - 10; }
    else if (z < 18) { W = m1; Wt = wm1; K = 512; mat = z - 14; }
    else             { W = m2; Wt = wm2; K = 256; mat = z - 18; }
    int k0 = blockIdx.x * 32;
    if (k0 >= K) return;
    const int C = 256;
    W  += (size_t)mat * K * C;
    Wt += (size_t)mat * K * C;
    int c0 = blockIdx.y * 32;
    int tx = threadIdx.x & 31, ty = threadIdx.x >> 5;
#pragma unroll
    for (int i = 0; i < 32; i += 8)
        tile[ty + i][tx] = W[(size_t)(k0 + ty + i) * C + c0 + tx];
    __syncthreads();
#pragma unroll
    for (int i = 0; i < 32; i += 8) {
        float vv = tile[tx][ty + i];
        Wt[(size_t)(c0 + ty + i) * K + k0 + tx] =
            __builtin_bit_cast(unsigned short, (__bf16)vv);
    }
}

// ---------------- enc1: fp32 in (x, K=128), bf16 out, ReLU+LN (64-row tile) ----------------
__global__ __launch_bounds__(256) void enc1_mfma(
    const float* __restrict__ in0, const unsigned short* __restrict__ Wt,
    const float* __restrict__ bias, const float* __restrict__ g,
    const float* __restrict__ be, unsigned short* __restrict__ outb, int n)
{
    constexpr int KTILE = 128, ROWB = 256;
    __shared__ __align__(16) char alds[64 * 256];
    __shared__ float red[4][64][2];
    int tid = threadIdx.x, lane = tid & 63, wv = tid >> 6;
    int cg = lane & 15, rg = lane >> 4;
    int base = blockIdx.x * 64;
    int cbase = wv * 64;

    f32x4 acc[4][4];
#pragma unroll
    for (int m = 0; m < 4; m++)
#pragma unroll
        for (int f = 0; f < 4; f++) acc[m][f] = (f32x4){0.f, 0.f, 0.f, 0.f};

#pragma unroll
    for (int i = 0; i < 8; i++) {
        int idx = (i * 256 + tid) * 4;
        int row = idx >> 7, k = idx & 127;
        int node = base + row;
        float4 v = {0.f, 0.f, 0.f, 0.f};
        if (node < n) v = *(const float4*)(in0 + (size_t)node * KTILE + k);
        uint2 pp; pp.x = pack_bf16(v.x, v.y); pp.y = pack_bf16(v.z, v.w);
        int off = row * ROWB + k * 2;
        off ^= (row & 7) << 4;
        *(uint2*)(alds + off) = pp;
    }
    __syncthreads();

#pragma unroll 2
    for (int k0 = 0; k0 < KTILE; k0 += 32) {
        b16x8 a[4], b[4];
#pragma unroll
        for (int m = 0; m < 4; m++) {
            int R = m * 16 + cg;
            int off = R * ROWB + (k0 + rg * 8) * 2;
            off ^= (R & 7) << 4;
            a[m] = __builtin_bit_cast(b16x8, *(const uint4*)(alds + off));
        }
#pragma unroll
        for (int f = 0; f < 4; f++) {
            const unsigned short* p = Wt + (size_t)(cbase + f * 16 + cg) * KTILE + k0 + rg * 8;
            b[f] = __builtin_bit_cast(b16x8, *(const uint4*)p);
        }
#pragma unroll
        for (int m = 0; m < 4; m++)
#pragma unroll
            for (int f = 0; f < 4; f++)
                acc[m][f] = mfma16(a[m], b[f], acc[m][f]);
    }

    float bias_v[4], g_v[4], be_v[4];
#pragma unroll
    for (int f = 0; f < 4; f++) {
        int col = cbase + f * 16 + cg;
        bias_v[f] = bias[col]; g_v[f] = g[col]; be_v[f] = be[col];
    }
#pragma unroll
    for (int m = 0; m < 4; m++)
#pragma unroll
        for (int f = 0; f < 4; f++)
#pragma unroll
            for (int r = 0; r < 4; r++)
                acc[m][f][r] = fmaxf(acc[m][f][r] + bias_v[f], 0.f);
#pragma unroll
    for (int m = 0; m < 4; m++)
#pragma unroll
        for (int r = 0; r < 4; r++) {
            float s = acc[m][0][r] + acc[m][1][r] + acc[m][2][r] + acc[m][3][r];
            float q = acc[m][0][r] * acc[m][0][r] + acc[m][1][r] * acc[m][1][r]
                    + acc[m][2][r] * acc[m][2][r] + acc[m][3][r] * acc[m][3][r];
#pragma unroll
            for (int o = 1; o < 16; o <<= 1) {
                s += __shfl_xor(s, o, 64); q += __shfl_xor(q, o, 64);
            }
            if (cg == 0) { int R = m * 16 + rg * 4 + r; red[wv][R][0] = s; red[wv][R][1] = q; }
        }
    __syncthreads();
#pragma unroll
    for (int m = 0; m < 4; m++)
#pragma unroll
        for (int r = 0; r < 4; r++) {
            int R = m * 16 + rg * 4 + r;
            float S = red[0][R][0] + red[1][R][0] + red[2][R][0] + red[3][R][0];
            float Q = red[0][R][1] + red[1][R][1] + red[2][R][1] + red[3][R][1];
            float mu = S * (1.f / HID);
            float rs = rsqrtf(Q * (1.f / HID) - mu * mu + EPSV);
            int row = base + R;
            if (row >= n) continue;
            size_t ro = (size_t)row * HID;
#pragma unroll
            for (int f = 0; f < 4; f++) {
                float v = (acc[m][f][r] - mu) * rs * g_v[f] + be_v[f];
                outb[ro + cbase + f * 16 + cg] = __builtin_bit_cast(unsigned short, (__bf16)v);
            }
        }
}

// ---------------- 128-row MFMA GEMM, bf16 in/out (enc2) ----------------
template<int NPASS, bool RELU_LN, bool ADD_RES, bool POS>
__global__ __launch_bounds__(256) void gemm128(
    const unsigned short* __restrict__ in0, const unsigned short* __restrict__ in1,
    const unsigned short* __restrict__ Wt, const float* __restrict__ bias,
    const float* __restrict__ g, const float* __restrict__ be,
    const unsigned short* __restrict__ addsrc, const float* __restrict__ pos_emb,
    const int* __restrict__ pidx, unsigned short* __restrict__ outb, int n)
{
    constexpr int KS = 256 * NPASS;
    __shared__ __align__(16) char alds[128 * 512];   // 64 KB
    __shared__ float red[4][128][2];

    int tid = threadIdx.x, lane = tid & 63, wv = tid >> 6;
    int cg = lane & 15, rg = lane >> 4;
    int base = blockIdx.x * 128;
    int cbase = wv * 64;

    f32x4 acc[2][4][4];
#pragma unroll
    for (int t = 0; t < 2; t++)
#pragma unroll
        for (int m = 0; m < 4; m++)
#pragma unroll
            for (int f = 0; f < 4; f++) acc[t][m][f] = (f32x4){0.f, 0.f, 0.f, 0.f};

    for (int pass = 0; pass < NPASS; pass++) {
        if (pass) __syncthreads();
        const unsigned short* src = pass ? in1 : in0;
        const unsigned short* Wp = Wt + pass * 256;

        stage_gld128(alds, src, base, tid);
        __syncthreads();

#pragma unroll
        for (int kk = 0; kk < 8; kk++) {
            b16x8 b[4];
#pragma unroll
            for (int f = 0; f < 4; f++)
                b[f] = __builtin_bit_cast(b16x8, *(const uint4*)(
                    Wp + (size_t)(cbase + f * 16 + cg) * KS + kk * 32 + rg * 8));
#pragma unroll
            for (int t = 0; t < 2; t++) {
                b16x8 a[4];
#pragma unroll
                for (int m = 0; m < 4; m++) {
                    int R = t * 64 + m * 16 + cg;
                    int off = R * 512 + (kk * 32 + rg * 8) * 2;
                    off ^= (R & 7) << 4;
                    a[m] = __builtin_bit_cast(b16x8, *(const uint4*)(alds + off));
                }
#pragma unroll
                for (int m = 0; m < 4; m++)
#pragma unroll
                    for (int f = 0; f < 4; f++)
                        acc[t][m][f] = mfma16(a[m], b[f], acc[t][m][f]);
            }
        }
    }

    float bias_v[4], g_v[4], be_v[4];
#pragma unroll
    for (int f = 0; f < 4; f++) {
        int col = cbase + f * 16 + cg;
        bias_v[f] = bias[col];
        if (RELU_LN) { g_v[f] = g[col]; be_v[f] = be[col]; }
    }
#pragma unroll
    for (int t = 0; t < 2; t++)
#pragma unroll
        for (int m = 0; m < 4; m++)
#pragma unroll
            for (int f = 0; f < 4; f++)
#pragma unroll
                for (int r = 0; r < 4; r++) acc[t][m][f][r] += bias_v[f];

    if (RELU_LN) {
#pragma unroll
        for (int t = 0; t < 2; t++)
#pragma unroll
            for (int m = 0; m < 4; m++)
#pragma unroll
                for (int f = 0; f < 4; f++)
#pragma unroll
                    for (int r = 0; r < 4; r++)
                        acc[t][m][f][r] = fmaxf(acc[t][m][f][r], 0.f);
#pragma unroll
        for (int t = 0; t < 2; t++)
#pragma unroll
            for (int m = 0; m < 4; m++)
#pragma unroll
                for (int r = 0; r < 4; r++) {
                    float s = acc[t][m][0][r] + acc[t][m][1][r] + acc[t][m][2][r] + acc[t][m][3][r];
                    float q = acc[t][m][0][r] * acc[t][m][0][r] + acc[t][m][1][r] * acc[t][m][1][r]
                            + acc[t][m][2][r] * acc[t][m][2][r] + acc[t][m][3][r] * acc[t][m][3][r];
#pragma unroll
                    for (int o = 1; o < 16; o <<= 1) {
                        s += __shfl_xor(s, o, 64); q += __shfl_xor(q, o, 64);
                    }
                    if (cg == 0) {
                        int R = t * 64 + m * 16 + rg * 4 + r;
                        red[wv][R][0] = s; red[wv][R][1] = q;
                    }
                }
        __syncthreads();
#pragma unroll
        for (int t = 0; t < 2; t++)
#pragma unroll
            for (int m = 0; m < 4; m++)
#pragma unroll
                for (int r = 0; r < 4; r++) {
                    int R = t * 64 + m * 16 + rg * 4 + r;
                    float S = red[0][R][0] + red[1][R][0] + red[2][R][0] + red[3][R][0];
                    float Q = red[0][R][1] + red[1][R][1] + red[2][R][1] + red[3][R][1];
                    float mu = S * (1.f / HID);
                    float rs = rsqrtf(Q * (1.f / HID) - mu * mu + EPSV);
#pragma unroll
                    for (int f = 0; f < 4; f++)
                        acc[t][m][f][r] = (acc[t][m][f][r] - mu) * rs * g_v[f] + be_v[f];
                }
    }

#pragma unroll
    for (int t = 0; t < 2; t++)
#pragma unroll
        for (int m = 0; m < 4; m++)
#pragma unroll
            for (int r = 0; r < 4; r++) {
                int row = base + t * 64 + m * 16 + rg * 4 + r;
                if (row >= n) continue;
                size_t ro = (size_t)row * HID;
                int pid = 0;
                if (POS) pid = pidx[row];
#pragma unroll
                for (int f = 0; f < 4; f++) {
                    int col = cbase + f * 16 + cg;
                    float v = acc[t][m][f][r];
                    if (ADD_RES) v += b2f(addsrc[ro + col]);
                    if (POS)     v += pos_emb[(size_t)pid * HID + col];
                    outb[ro + col] = __builtin_bit_cast(unsigned short, (__bf16)v);
                }
            }
}

// ---------------- fused MLP: double-buffered half-tile pipeline ----------------
// mlp1 K=512 split into 4 half-tiles of 128x128 (32KB each). stage(ht+1) issued
// BEFORE compute(ht) so loads fly under the MFMA burst. Buffer selected via
// compile-time-foldable offset (no LDS pointer array - hipcc static-init limit).
__global__ __launch_bounds__(256) void mlp_fused(
    const unsigned short* __restrict__ h16, const unsigned short* __restrict__ a16,
    const unsigned short* __restrict__ Wt1, const float* __restrict__ b1,
    const float* __restrict__ g, const float* __restrict__ be,
    const unsigned short* __restrict__ Wt2, const float* __restrict__ b2,
    unsigned short* __restrict__ hout, int n)
{
    __shared__ __align__(16) char alds[128 * 512];   // 64 KB total (2x 32KB halves)
    __shared__ float red[4][128][2];
    int tid = threadIdx.x, lane = tid & 63, wv = tid >> 6;
    int cg = lane & 15, rg = lane >> 4;
    int base = blockIdx.x * 128;
    int cbase = wv * 64;

    f32x4 acc[2][4][4];
#pragma unroll
    for (int t = 0; t < 2; t++)
#pragma unroll
        for (int m = 0; m < 4; m++)
#pragma unroll
            for (int f = 0; f < 4; f++) acc[t][m][f] = (f32x4){0.f, 0.f, 0.f, 0.f};

    // prologue: stage half-tile 0 (h16, cols 0-127) into buffer 0
    stage_half(alds, h16, base, 0, tid);
    __syncthreads();

#pragma unroll
    for (int ht = 0; ht < 4; ht++) {
        // issue next half-tile's loads before computing this one
        if (ht < 3) {
            const unsigned short* s = (ht + 1 < 2) ? h16 : a16;
            int cb = ((ht + 1) & 1) * 128;
            stage_half(alds + (((ht + 1) & 1) << 15), s, base, cb, tid);
        }
        const char* buf = alds + ((ht & 1) << 15);
#pragma unroll
        for (int kk = 0; kk < 4; kk++) {
            b16x8 b[4];
#pragma unroll
            for (int f = 0; f < 4; f++)
                b[f] = __builtin_bit_cast(b16x8, *(const uint4*)(
                    Wt1 + (size_t)(cbase + f * 16 + cg) * 512 + ht * 128 + kk * 32 + rg * 8));
#pragma unroll
            for (int t = 0; t < 2; t++) {
                b16x8 a[4];
#pragma unroll
                for (int m = 0; m < 4; m++) {
                    int R = t * 64 + m * 16 + cg;
                    int off = R * 256 + (kk * 32 + rg * 8) * 2;
                    off ^= (R & 7) << 4;
                    a[m] = __builtin_bit_cast(b16x8, *(const uint4*)(buf + off));
                }
#pragma unroll
                for (int m = 0; m < 4; m++)
#pragma unroll
                    for (int f = 0; f < 4; f++)
                        acc[t][m][f] = mfma16(a[m], b[f], acc[t][m][f]);
            }
        }
        __syncthreads();   // all waves done reading buf; next stage's loads drained
    }

    // bias + relu + LN
    float b1_v[4], g_v[4], be_v[4];
#pragma unroll
    for (int f = 0; f < 4; f++) {
        int col = cbase + f * 16 + cg;
        b1_v[f] = b1[col]; g_v[f] = g[col]; be_v[f] = be[col];
    }
#pragma unroll
    for (int t = 0; t < 2; t++)
#pragma unroll
        for (int m = 0; m < 4; m++)
#pragma unroll
            for (int f = 0; f < 4; f++)
#pragma unroll
                for (int r = 0; r < 4; r++)
                    acc[t][m][f][r] = fmaxf(acc[t][m][f][r] + b1_v[f], 0.f);
#pragma unroll
    for (int t = 0; t < 2; t++)
#pragma unroll
        for (int m = 0; m < 4; m++)
#pragma unroll
            for (int r = 0; r < 4; r++) {
                float s = acc[t][m][0][r] + acc[t][m][1][r] + acc[t][m][2][r] + acc[t][m][3][r];
                float q = acc[t][m][0][r] * acc[t][m][0][r] + acc[t][m][1][r] * acc[t][m][1][r]
                        + acc[t][m][2][r] * acc[t][m][2][r] + acc[t][m][3][r] * acc[t][m][3][r];
#pragma unroll
                for (int o = 1; o < 16; o <<= 1) {
                    s += __shfl_xor(s, o, 64); q += __shfl_xor(q, o, 64);
                }
                if (cg == 0) {
                    int R = t * 64 + m * 16 + rg * 4 + r;
                    red[wv][R][0] = s; red[wv][R][1] = q;
                }
            }
    __syncthreads();
#pragma unroll
    for (int t = 0; t < 2; t++)
#pragma unroll
        for (int m = 0; m < 4; m++)
#pragma unroll
            for (int r = 0; r < 4; r++) {
                int R = t * 64 + m * 16 + rg * 4 + r;
                float S = red[0][R][0] + red[1][R][0] + red[2][R][0] + red[3][R][0];
                float Q = red[0][R][1] + red[1][R][1] + red[2][R][1] + red[3][R][1];
                float mu = S * (1.f / HID);
                float rs = rsqrtf(Q * (1.f / HID) - mu * mu + EPSV);
#pragma unroll
                for (int f = 0; f < 4; f++)
                    acc[t][m][f][r] = (acc[t][m][f][r] - mu) * rs * g_v[f] + be_v[f];
            }

    // write LN'ed M-tile (bf16) into the full 64KB LDS (ROWB=512 swizzled layout)
    __syncthreads();
#pragma unroll
    for (int t = 0; t < 2; t++)
#pragma unroll
        for (int m = 0; m < 4; m++)
#pragma unroll
            for (int r = 0; r < 4; r++) {
                int R = t * 64 + m * 16 + rg * 4 + r;
#pragma unroll
                for (int f = 0; f < 4; f++) {
                    int col = cbase + f * 16 + cg;
                    int off = R * 512 + col * 2;
                    off ^= (R & 7) << 4;
                    *(unsigned short*)(alds + off) =
                        __builtin_bit_cast(unsigned short, (__bf16)acc[t][m][f][r]);
                }
            }
    __syncthreads();

    // mlp2 pass from LDS + residual
#pragma unroll
    for (int t = 0; t < 2; t++)
#pragma unroll
        for (int m = 0; m < 4; m++)
#pragma unroll
            for (int f = 0; f < 4; f++) acc[t][m][f] = (f32x4){0.f, 0.f, 0.f, 0.f};
#pragma unroll
    for (int kk = 0; kk < 8; kk++) {
        b16x8 b[4];
#pragma unroll
        for (int f = 0; f < 4; f++)
            b[f] = __builtin_bit_cast(b16x8, *(const uint4*)(
                Wt2 + (size_t)(cbase + f * 16 + cg) * 256 + kk * 32 + rg * 8));
#pragma unroll
        for (int t = 0; t < 2; t++) {
            b16x8 a[4];
#pragma unroll
            for (int m = 0; m < 4; m++) {
                int R = t * 64 + m * 16 + cg;
                int off = R * 512 + (kk * 32 + rg * 8) * 2;
                off ^= (R & 7) << 4;
                a[m] = __builtin_bit_cast(b16x8, *(const uint4*)(alds + off));
            }
#pragma unroll
            for (int m = 0; m < 4; m++)
#pragma unroll
                for (int f = 0; f < 4; f++)
                    acc[t][m][f] = mfma16(a[m], b[f], acc[t][m][f]);
        }
    }

    float b2_v[4];
#pragma unroll
    for (int f = 0; f < 4; f++) b2_v[f] = b2[cbase + f * 16 + cg];
#pragma unroll
    for (int t = 0; t < 2; t++)
#pragma unroll
        for (int m = 0; m < 4; m++)
#pragma unroll
            for (int r = 0; r < 4; r++) {
                int row = base + t * 64 + m * 16 + rg * 4 + r;
                if (row >= n) continue;
                size_t ro = (size_t)row * HID;
#pragma unroll
                for (int f = 0; f < 4; f++) {
                    int col = cbase + f * 16 + cg;
                    float v = acc[t][m][f][r] + b2_v[f] + b2f(hout[ro + col]);
                    hout[ro + col] = __builtin_bit_cast(unsigned short, (__bf16)v);
                }
            }
}

// ---------------- QKV, 128-row tile, 3-way split; K/V interleaved into KV[node][512] ----------------
__global__ __launch_bounds__(256) void qkv128_kernel(
    const unsigned short* __restrict__ hsrc,
    const unsigned short* __restrict__ Wtq, const unsigned short* __restrict__ Wtk,
    const unsigned short* __restrict__ Wtv,
    const float* __restrict__ bq, const float* __restrict__ bk, const float* __restrict__ bv,
    unsigned short* __restrict__ Qo, unsigned short* __restrict__ KVo, int n)
{
    __shared__ __align__(16) char alds[128 * 512];   // 64 KB
    int tid = threadIdx.x, lane = tid & 63, wv = tid >> 6;
    int cg = lane & 15, rg = lane >> 4;
    int base = blockIdx.x * 128;
    int cbase = wv * 64;
    int mat = blockIdx.y;
    const unsigned short* Wp = (mat == 0) ? Wtq : (mat == 1) ? Wtk : Wtv;
    const float* bp = (mat == 0) ? bq : (mat == 1) ? bk : bv;
    unsigned short* op = (mat == 0) ? Qo : KVo;
    int ostride = (mat == 0) ? HID : 512;
    int coff = (mat == 2) ? 256 : 0;

    stage_gld128(alds, hsrc, base, tid);
    __syncthreads();

    f32x4 acc[2][4][4];
#pragma unroll
    for (int t = 0; t < 2; t++)
#pragma unroll
        for (int m = 0; m < 4; m++)
#pragma unroll
            for (int f = 0; f < 4; f++) acc[t][m][f] = (f32x4){0.f, 0.f, 0.f, 0.f};

#pragma unroll
    for (int kk = 0; kk < 8; kk++) {
        b16x8 b[4];
#pragma unroll
        for (int f = 0; f < 4; f++)
            b[f] = __builtin_bit_cast(b16x8, *(const uint4*)(
                Wp + (size_t)(cbase + f * 16 + cg) * 256 + kk * 32 + rg * 8));
#pragma unroll
        for (int t = 0; t < 2; t++) {
            b16x8 a[4];
#pragma unroll
            for (int m = 0; m < 4; m++) {
                int R = t * 64 + m * 16 + cg;
                int off = R * 512 + (kk * 32 + rg * 8) * 2;
                off ^= (R & 7) << 4;
                a[m] = __builtin_bit_cast(b16x8, *(const uint4*)(alds + off));
            }
#pragma unroll
            for (int m = 0; m < 4; m++)
#pragma unroll
                for (int f = 0; f < 4; f++)
                    acc[t][m][f] = mfma16(a[m], b[f], acc[t][m][f]);
        }
    }

    float bias_v[4];
#pragma unroll
    for (int f = 0; f < 4; f++) bias_v[f] = bp[cbase + f * 16 + cg];
#pragma unroll
    for (int t = 0; t < 2; t++)
#pragma unroll
        for (int m = 0; m < 4; m++)
#pragma unroll
            for (int r = 0; r < 4; r++) {
                int row = base + t * 64 + m * 16 + rg * 4 + r;
                if (row >= n) continue;
                size_t ro = (size_t)row * ostride + coff;
#pragma unroll
                for (int f = 0; f < 4; f++) {
                    float v = acc[t][m][f][r] + bias_v[f];
                    op[ro + cbase + f * 16 + cg] =
                        __builtin_bit_cast(unsigned short, (__bf16)v);
                }
            }
}

// ---------------- CSR build ----------------
__global__ void count_kernel(const int* __restrict__ row, int* __restrict__ counts, int e)
{
    int i = blockIdx.x * blockDim.x + threadIdx.x;
    if (i < e) atomicAdd(&counts[row[i]], 1);
}

__global__ __launch_bounds__(256) void scan1_kernel(const int* __restrict__ counts,
    int* __restrict__ offs, int* __restrict__ bsum, int n)
{
    __shared__ int wsumS[4];
    int tid = threadIdx.x, b = blockIdx.x;
    int i = b * 256 + tid;
    int v = (i < n) ? counts[i] : 0;
    int lane = tid & 63, wv = tid >> 6;
    int s = v;
#pragma unroll
    for (int o = 1; o < 64; o <<= 1) { int t = __shfl_up(s, o, 64); if (lane >= o) s += t; }
    if (lane == 63) wsumS[wv] = s;
    __syncthreads();
    int add = 0;
    for (int j = 0; j < wv; j++) add += wsumS[j];
    s += add;
    if (i < n) offs[i + 1] = s;
    if (tid == 255) bsum[b] = s;
}

__global__ __launch_bounds__(256) void scan2_kernel(int* __restrict__ bsum, int nb)
{
    __shared__ int wsumS[4];
    int tid = threadIdx.x;
    int v = (tid < nb) ? bsum[tid] : 0;
    int lane = tid & 63, wv = tid >> 6;
    int s = v;
#pragma unroll
    for (int o = 1; o < 64; o <<= 1) { int t = __shfl_up(s, o, 64); if (lane >= o) s += t; }
    if (lane == 63) wsumS[wv] = s;
    __syncthreads();
    int add = 0;
    for (int j = 0; j < wv; j++) add += wsumS[j];
    s += add;
    if (tid < nb) bsum[tid] = s;
}

__global__ __launch_bounds__(256) void scan3_kernel(int* __restrict__ offs,
    const int* __restrict__ bsum, int n)
{
    int tid = threadIdx.x, b = blockIdx.x;
    int i = b * 256 + tid;
    if (i == 0) offs[0] = 0;
    if (i < n && b > 0) offs[i + 1] += bsum[b - 1];
}

__global__ void scatter_kernel(const int* __restrict__ row, const int* __restrict__ col,
    const int* __restrict__ offs, int* __restrict__ cur, int* __restrict__ ccol, int e)
{
    int i = blockIdx.x * blockDim.x + threadIdx.x;
    if (i >= e) return;
    int r = row[i];
    int pos = atomicAdd(&cur[r], 1);
    ccol[offs[r] + pos] = col[i];
}

// ---------------- attention: full wave per node, 2-way edge split, interleaved KV ----------------
__global__ __launch_bounds__(256) void attn_fw_kernel(
    const unsigned short* __restrict__ Qm, const unsigned short* __restrict__ KV,
    const int* __restrict__ offs, const int* __restrict__ ccol,
    unsigned short* __restrict__ agg, int n)
{
    int tid = threadIdx.x;
    int wv = tid >> 6;
    int lane = tid & 63;
    int half = lane >> 5;
    int l32 = lane & 31;
    int node = blockIdx.x * 4 + wv;
    if (node >= n) return;
    int start = offs[node], fin = offs[node + 1];
    size_t rowoff = (size_t)node * HID + l32 * 8;
    if (start == fin) {
        if (half == 0) {
            uint4 z = {0u, 0u, 0u, 0u};
            *(uint4*)(agg + rowoff) = z;
        }
        return;
    }

    uint4 qr = *(const uint4*)(Qm + rowoff);
    float qf[8];
    unpack2(qr.x, qf[0], qf[1]);
    unpack2(qr.y, qf[2], qf[3]);
    unpack2(qr.z, qf[4], qf[5]);
    unpack2(qr.w, qf[6], qf[7]);

    float m = -3.0e38f, d = 0.f;
    float acc[8];
#pragma unroll
    for (int j = 0; j < 8; j++) acc[j] = 0.f;

    for (int i = start + half; i < fin; i += 2) {
        int c = ccol[i];
        const unsigned short* kvp = KV + (size_t)c * 512 + l32 * 8;
        uint4 kr = *(const uint4*)kvp;
        uint4 vr = *(const uint4*)(kvp + 256);
        float k0, k1, k2, k3, k4, k5, k6, k7;
        unpack2(kr.x, k0, k1); unpack2(kr.y, k2, k3);
        unpack2(kr.z, k4, k5); unpack2(kr.w, k6, k7);
        float p = qf[0] * k0 + qf[1] * k1 + qf[2] * k2 + qf[3] * k3
                + qf[4] * k4 + qf[5] * k5 + qf[6] * k6 + qf[7] * k7;
        p += __shfl_xor(p, 1, 64);
        p += __shfl_xor(p, 2, 64);
        p += __shfl_xor(p, 4, 64);
        float s = p * 0.125f;
        float mn = fmaxf(m, s);
        float sc = __expf(m - mn);
        float w = __expf(s - mn);
        d = d * sc + w;
        float v0, v1, v2, v3, v4, v5, v6, v7;
        unpack2(vr.x, v0, v1); unpack2(vr.y, v2, v3);
        unpack2(vr.z, v4, v5); unpack2(vr.w, v6, v7);
        acc[0] = acc[0] * sc + w * v0;  acc[1] = acc[1] * sc + w * v1;
        acc[2] = acc[2] * sc + w * v2;  acc[3] = acc[3] * sc + w * v3;
        acc[4] = acc[4] * sc + w * v4;  acc[5] = acc[5] * sc + w * v5;
        acc[6] = acc[6] * sc + w * v6;  acc[7] = acc[7] * sc + w * v7;
        m = mn;
    }

    float mo = __shfl_xor(m, 32, 64);
    float M = fmaxf(m, mo);
    float fs = __expf(m - M);
    float fo = __expf(mo - M);
    float D = d * fs + __shfl_xor(d, 32, 64) * fo;
    float inv = 1.f / D;
#pragma unroll
    for (int j = 0; j < 8; j++) {
        float other = __shfl_xor(acc[j], 32, 64);
        acc[j] = (acc[j] * fs + other * fo) * inv;
    }

    if (half == 0) {
        uint4 out;
        out.x = pack_bf16(acc[0], acc[1]);
        out.y = pack_bf16(acc[2], acc[3]);
        out.z = pack_bf16(acc[4], acc[5]);
        out.w = pack_bf16(acc[6], acc[7]);
        *(uint4*)(agg + rowoff) = out;
    }
}

// ---------------- pooling (two-stage parallel, bf16 input) ----------------
__global__ void bounds_kernel(const int* __restrict__ batch, int* __restrict__ gb, int n)
{
    int g = threadIdx.x;
    if (g > GRAPHS) return;
    int lo = 0, hi = n;
    while (lo < hi) { int mid = (lo + hi) >> 1; if (batch[mid] < g) lo = mid + 1; else hi = mid; }
    gb[g] = lo;
}

__global__ __launch_bounds__(256) void pool_partial_kernel(
    const unsigned short* __restrict__ h16,
    const int* __restrict__ gb, float* __restrict__ partial)
{
    int s = blockIdx.x, g = blockIdx.y, tid = threadIdx.x;
    int lo = gb[g], hi = gb[g + 1];
    float sum = 0.f;
    for (int i = lo + s; i < hi; i += PSPLIT)
        sum += b2f(h16[(size_t)i * HID + tid]);
    partial[((size_t)g * PSPLIT + s) * HID + tid] = sum;
}

__global__ __launch_bounds__(256) void pool_reduce_kernel(const float* __restrict__ partial,
    const int* __restrict__ gb, float* __restrict__ pooled)
{
    int g = blockIdx.x, tid = threadIdx.x;
    float sum = 0.f;
#pragma unroll
    for (int s = 0; s < PSPLIT; s++) sum += partial[((size_t)g * PSPLIT + s) * HID + tid];
    int cnt = gb[g + 1] - gb[g];
    pooled[g * HID + tid] = sum / fmaxf((float)cnt, 1.f);
}

// ---------------- classifier ----------------
__global__ __launch_bounds__(256) void cls_kernel(const float* __restrict__ pooled,
    const float* __restrict__ W1, const float* __restrict__ b1,
    const float* __restrict__ g, const float* __restrict__ be,
    const float* __restrict__ W2, const float* __restrict__ b2,
    float* __restrict__ out)
{
    __shared__ float pin[HID];
    __shared__ float hbuf[HID];
    __shared__ float red2[4][2];
    int tid = threadIdx.x, gi = blockIdx.x;
    int lane = tid & 63, wv = tid >> 6;
    pin[tid] = pooled[gi * HID + tid];
    __syncthreads();
    float acc = 0.f;
    for (int k = 0; k < HID; k++) acc += pin[k] * W1[k * HID + tid];
    acc = fmaxf(acc + b1[tid], 0.f);
    float s = acc, q = acc * acc;
#pragma unroll
    for (int o = 1; o < 64; o <<= 1) { s += __shfl_xor(s, o, 64); q += __shfl_xor(q, o, 64); }
    if (lane == 0) { red2[wv][0] = s; red2[wv][1] = q; }
    __syncthreads();
    float S = red2[0][0] + red2[1][0] + red2[2][0] + red2[3][0];
    float Q = red2[0][1] + red2[1][1] + red2[2][1] + red2[3][1];
    float mu = S * (1.f / HID);
    float rs = rsqrtf(Q * (1.f / HID) - mu * mu + EPSV);
    hbuf[tid] = (acc - mu) * rs * g[tid] + be[tid];
    __syncthreads();
    if (tid < OUTC) {
        float o = 0.f;
        for (int k = 0; k < HID; k++) o += hbuf[k] * W2[k * OUTC + tid];
        out[gi * OUTC + tid] = o + b2[tid];
    }
}

// ---------------- host launch ----------------
extern "C" void kernel_launch(void* const* d_in, const int* in_sizes, int n_in,
                              void* d_out, int out_size, void* d_ws, size_t ws_size,
                              hipStream_t stream)
{
    const float* x        = (const float*)d_in[0];
    const int*   ei       = (const int*)d_in[1];
    const int*   pidx     = (const int*)d_in[2];
    const int*   batch    = (const int*)d_in[3];
    const float* enc_w1   = (const float*)d_in[4];
    const float* enc_b1   = (const float*)d_in[5];
    const float* enc_g    = (const float*)d_in[6];
    const float* enc_beta = (const float*)d_in[7];
    const float* enc_w2   = (const float*)d_in[8];
    const float* enc_b2   = (const float*)d_in[9];
    const float* pos_emb  = (const float*)d_in[10];
    const float* Wq       = (const float*)d_in[11];
    const float* bq       = (const float*)d_in[12];
    const float* Wk       = (const float*)d_in[13];
    const float* bk       = (const float*)d_in[14];
    const float* Wv       = (const float*)d_in[15];
    const float* bv       = (const float*)d_in[16];
    const float* mlp_w1   = (const float*)d_in[17];
    const float* mlp_b1   = (const float*)d_in[18];
    const float* mlp_g    = (const float*)d_in[19];
    const float* mlp_beta = (const float*)d_in[20];
    const float* mlp_w2   = (const float*)d_in[21];
    const float* mlp_b2   = (const float*)d_in[22];
    const float* cls_w1   = (const float*)d_in[23];
    const float* cls_b1   = (const float*)d_in[24];
    const float* cls_g    = (const float*)d_in[25];
    const float* cls_beta = (const float*)d_in[26];
    const float* cls_w2   = (const float*)d_in[27];
    const float* cls_b2   = (const float*)d_in[28];

    int n = in_sizes[2];            // 50000
    int e = in_sizes[1] / 2;        // 800000
    const int* row = ei;
    const int* col = ei + e;

    char* p = (char*)d_ws;
    auto alloc = [&](size_t bytes) -> void* {
        void* r = (void*)p;
        p += (bytes + 255) & ~(size_t)255;
        return r;
    };
    size_t NH = (size_t)n * HID;
    unsigned short* h16  = (unsigned short*)alloc(NH * 2);
    unsigned short* a16  = (unsigned short*)alloc(NH * 2);
    unsigned short* m16  = (unsigned short*)alloc(NH * 2);
    unsigned short* Qb   = (unsigned short*)alloc(NH * 2);
    unsigned short* KVb  = (unsigned short*)alloc(NH * 4);   // K/V interleaved [n][512]
    float* partial = (float*)alloc((size_t)GRAPHS * PSPLIT * HID * 4);
    float* pooled  = (float*)alloc((size_t)GRAPHS * HID * 4);
    int* counts = (int*)alloc((size_t)n * 4);
    int* offs   = (int*)alloc((size_t)(n + 1) * 4);
    int* cur    = (int*)alloc((size_t)n * 4);
    int* ccol   = (int*)alloc((size_t)e * 4);
    int* bsum   = (int*)alloc(1024);
    int* gb     = (int*)alloc((GRAPHS + 1) * 4);
    unsigned short* wt_e1 = (unsigned short*)alloc((size_t)128 * 256 * 2);
    unsigned short* wt_e2 = (unsigned short*)alloc((size_t)256 * 256 * 2);
    unsigned short* wt_q  = (unsigned short*)alloc((size_t)4 * 256 * 256 * 2);
    unsigned short* wt_k  = (unsigned short*)alloc((size_t)4 * 256 * 256 * 2);
    unsigned short* wt_v  = (unsigned short*)alloc((size_t)4 * 256 * 256 * 2);
    unsigned short* wt_m1 = (unsigned short*)alloc((size_t)4 * 512 * 256 * 2);
    unsigned short* wt_m2 = (unsigned short*)alloc((size_t)4 * 256 * 256 * 2);

    int gblocks64  = (n + 63) / 64;
    int gblocks128 = (n + 127) / 128;
    int nb = (n + 255) / 256;

    // ---- weight prep (single launch) ----
    wtrans_all<<<dim3(16, 8, 22), 256, 0, stream>>>(
        enc_w1, enc_w2, Wq, Wk, Wv, mlp_w1, mlp_w2,
        wt_e1, wt_e2, wt_q, wt_k, wt_v, wt_m1, wt_m2);

    // ---- CSR build ----
    hipMemsetAsync(counts, 0, (size_t)n * 4, stream);
    hipMemsetAsync(cur, 0, (size_t)n * 4, stream);
    count_kernel<<<(e + 255) / 256, 256, 0, stream>>>(row, counts, e);
    scan1_kernel<<<nb, 256, 0, stream>>>(counts, offs, bsum, n);
    scan2_kernel<<<1, 256, 0, stream>>>(bsum, nb);
    scan3_kernel<<<nb, 256, 0, stream>>>(offs, bsum, n);
    scatter_kernel<<<(e + 255) / 256, 256, 0, stream>>>(row, col, offs, cur, ccol, e);
    bounds_kernel<<<1, 128, 0, stream>>>(batch, gb, n);

    // ---- encoder ----
    enc1_mfma<<<gblocks64, 256, 0, stream>>>(x, wt_e1, enc_b1, enc_g, enc_beta, m16, n);
    gemm128<1, false, false, true><<<gblocks128, 256, 0, stream>>>(
        m16, nullptr, wt_e2, enc_b2, nullptr, nullptr, nullptr, pos_emb, pidx, h16, n);

    // ---- attention layers ----
    int ablocks = (n + 3) / 4;
    for (int l = 0; l < 4; l++) {
        size_t wo = (size_t)l * 256 * 256;
        size_t bo = (size_t)l * HID;
        qkv128_kernel<<<dim3(gblocks128, 3), 256, 0, stream>>>(
            h16, wt_q + wo, wt_k + wo, wt_v + wo, bq + bo, bk + bo, bv + bo,
            Qb, KVb, n);
        attn_fw_kernel<<<ablocks, 256, 0, stream>>>(Qb, KVb, offs, ccol, a16, n);
        mlp_fused<<<gblocks128, 256, 0, stream>>>(
            h16, a16, wt_m1 + (size_t)l * 512 * 256, mlp_b1 + bo,
            mlp_g + bo, mlp_beta + bo, wt_m2 + wo, mlp_b2 + bo, h16, n);
    }

    // ---- pool + classifier ----
    pool_partial_kernel<<<dim3(PSPLIT, GRAPHS), 256, 0, stream>>>(h16, gb, partial);
    pool_reduce_kernel<<<GRAPHS, 256, 0, stream>>>(partial, gb, pooled);
    cls_kernel<<<GRAPHS, 256, 0, stream>>>(pooled, cls_w1, cls_b1, cls_g, cls_beta,
                                           cls_w2, cls_b2, (float*)d_out);
}